// Round 9
// baseline (391.253 us; speedup 1.0000x reference)
//
#include <hip/hip_runtime.h>
#include <cstdint>
#include <cstddef>

// ---------------------------------------------------------------------------
// GCN: 5 layers, out = Â (x W) + b per layer, SiLU on layers 0-3.
// Â = D^-1/2 (A + I) D^-1/2 built from edge_index with self-loops.
//  - aggregate in the LOWEST-dim space (linearity): layer 0 aggregates the
//    3-dim input; layer 4's 128->3 matmul is fused into layer 3's GEMM
//    epilogue (PROJ) so layer 4 aggregates 3-dim.
//  - CSR build via LDS-binned multisplit; col as ushort, PADDED to 4-edge
//    alignment per node (pads -> zeroed row N) so aggregation does pure
//    ushort4 index loads (round-9: test VMEM-issue vs TCP-miss-slot theory).
//  - 128-dim aggregation: column-blocked layout [8][N+1][16] + XCD-pinned
//    slices (blockIdx&7 -> XCD): L2-resident gather, 8 nodes/wave, 4 chains.
//  - GEMM: W (64 KB) resident in LDS, barrier-free main loop, unroll 2 ONLY
//    (round-5 lesson: full unroll -> scratch spill -> 20x regression).
// ---------------------------------------------------------------------------

#define NB_SPLIT 256          // workgroups in prep/split passes
#define BUCKET_SHIFT 7        // 128 nodes per bucket

static __device__ __forceinline__ float silu_f(float x) {
  return x / (1.0f + __expf(-x));
}

// Pass A: pack edges to 4B records + per-(bucket, wg) histogram.
// Layout detection (int64 vs int32) folded in: odd 32-bit words all zero
// over the first 256 entries -> int64.
__global__ __launch_bounds__(256) void k_prep(
    const int* __restrict__ e32, int* __restrict__ epack, int* __restrict__ cnt2,
    int E, int nbucket, int chunk) {
  __shared__ int hist[512];
  __shared__ int nz;
  const int w = blockIdx.x, t = threadIdx.x;
  for (int b = t; b < nbucket; b += 256) hist[b] = 0;
  if (t == 0) nz = 0;
  __syncthreads();
  if (e32[t * 2 + 1] != 0) nz = 1;
  __syncthreads();
  const int f = nz ? 0 : 1;            // 1 -> int64 layout
  const int i0 = w * chunk;
  const int i1 = min(E, i0 + chunk);
  for (int i = i0 + t; i < i1; i += 256) {
    int s, d;
    if (f) { s = e32[2 * i]; d = e32[2 * E + 2 * i]; }
    else   { s = e32[i];     d = e32[E + i]; }
    epack[i] = s | (d << 16);            // requires N <= 65536 (N = 50000)
    atomicAdd(&hist[d >> BUCKET_SHIFT], 1);
  }
  __syncthreads();
  for (int b = t; b < nbucket; b += 256) cnt2[b * NB_SPLIT + w] = hist[b];
}

// Hierarchical exclusive scan, stage 1: 1024 elems/block (4/thread).
__global__ void k_scan1(const int* __restrict__ cnt, int* __restrict__ outp,
                        int* __restrict__ bsum, int n) {
  __shared__ int wsum[4];
  const int t = threadIdx.x;
  const int base = blockIdx.x * 1024 + t * 4;
  int v0 = 0, v1 = 0, v2 = 0, v3 = 0;
  if (base + 0 < n) v0 = cnt[base + 0];
  if (base + 1 < n) v1 = cnt[base + 1];
  if (base + 2 < n) v2 = cnt[base + 2];
  if (base + 3 < n) v3 = cnt[base + 3];
  const int s = v0 + v1 + v2 + v3;
  int sc = s;
  const int lane = t & 63;
  #pragma unroll
  for (int o = 1; o < 64; o <<= 1) {
    int u = __shfl_up(sc, o);
    if (lane >= o) sc += u;
  }
  const int wid = t >> 6;
  if (lane == 63) wsum[wid] = sc;
  __syncthreads();
  int wbase = 0;
  for (int w = 0; w < wid; ++w) wbase += wsum[w];
  const int ex = wbase + sc - s;
  if (base + 0 < n) outp[base + 0] = ex;
  if (base + 1 < n) outp[base + 1] = ex + v0;
  if (base + 2 < n) outp[base + 2] = ex + v0 + v1;
  if (base + 3 < n) outp[base + 3] = ex + v0 + v1 + v2;
  if (t == 0) bsum[blockIdx.x] = wsum[0] + wsum[1] + wsum[2] + wsum[3];
}

// Stage 2: serial exclusive scan of block sums (small).
__global__ void k_scan2(int* __restrict__ bsum, int nblk) {
  if (threadIdx.x == 0 && blockIdx.x == 0) {
    int acc = 0;
    for (int i = 0; i < nblk; ++i) { int v = bsum[i]; bsum[i] = acc; acc += v; }
  }
}

// Stage 3: add block offsets.
__global__ void k_scanadd(int* __restrict__ arr, const int* __restrict__ bsum, int n) {
  int i = blockIdx.x * blockDim.x + threadIdx.x;
  if (i < n) arr[i] += bsum[i >> 10];
}

// Pass B: scatter packed edges into bucket-grouped tmp; each (wg,bucket) owns
// a private contiguous sub-region -> L2 merges the 4B writes into full lines.
__global__ __launch_bounds__(256) void k_split(
    const int* __restrict__ epack, const int* __restrict__ off2,
    int* __restrict__ tmp, int E, int nbucket, int chunk) {
  __shared__ int cur[512];
  const int w = blockIdx.x, t = threadIdx.x;
  for (int b = t; b < nbucket; b += 256) cur[b] = off2[b * NB_SPLIT + w];
  __syncthreads();
  const int i0 = w * chunk;
  const int i1 = min(E, i0 + chunk);
  for (int i = i0 + t; i < i1; i += 256) {
    int p = epack[i];
    int b = (int)(((unsigned)p) >> (16 + BUCKET_SHIFT));
    int pos = atomicAdd(&cur[b], 1);
    tmp[pos] = p;
  }
}

// Pass C1: per bucket, per-node degree histogram from the bucket stream;
// store counts + padded bucket total (each node padded to multiple of 4).
__global__ __launch_bounds__(256) void k_csrA(
    const int* __restrict__ tmp, const int* __restrict__ off2,
    int* __restrict__ cnt_g, int* __restrict__ bpad, int E, int nbucket) {
  __shared__ int lcnt[128];
  __shared__ int tot;
  const int b = blockIdx.x, t = threadIdx.x;
  if (t < 128) lcnt[t] = 0;
  if (t == 0) tot = 0;
  __syncthreads();
  const int s0 = off2[b * NB_SPLIT];
  const int s1 = (b + 1 < nbucket) ? off2[(b + 1) * NB_SPLIT] : E;
  for (int i = s0 + t; i < s1; i += 256) {
    atomicAdd(&lcnt[((unsigned)tmp[i] >> 16) & 127u], 1);
  }
  __syncthreads();
  if (t < 128) {
    int v = lcnt[t];
    cnt_g[b * 128 + t] = v;
    atomicAdd(&tot, (v + 3) & ~3);
  }
  __syncthreads();
  if (t == 0) bpad[b] = tot;
}

// Pass C2: exclusive scan of padded bucket totals (nbucket ~ 391); also sets
// rowp[N] = padded grand total.
__global__ void k_bscan(int* __restrict__ bpad, int nbucket,
                        int* __restrict__ rowp, int N) {
  if (threadIdx.x == 0 && blockIdx.x == 0) {
    int acc = 0;
    for (int i = 0; i < nbucket; ++i) { int v = bpad[i]; bpad[i] = acc; acc += v; }
    bpad[nbucket] = acc;
    rowp[N] = acc;
  }
}

// Pass C3: per bucket, padded local scan -> rowp/dis/pad-fill, then place
// edges into the padded col array (pads point at zero row N).
__global__ __launch_bounds__(256) void k_csrB(
    const int* __restrict__ tmp, const int* __restrict__ off2,
    const int* __restrict__ cnt_g, const int* __restrict__ bpad,
    int* __restrict__ rowp, float* __restrict__ dis,
    unsigned short* __restrict__ col, int E, int nbucket, int N) {
  __shared__ int lcur[128];
  __shared__ int wtot;
  const int b = blockIdx.x, t = threadIdx.x;
  const int nb0 = b << BUCKET_SHIFT;
  const int nn = min(1 << BUCKET_SHIFT, N - nb0);
  int v = 0, pv = 0, sc = 0;
  if (t < 128) {
    v = cnt_g[b * 128 + t];
    pv = (v + 3) & ~3;
    sc = pv;
    #pragma unroll
    for (int o = 1; o < 64; o <<= 1) {
      int u = __shfl_up(sc, o);
      if ((t & 63) >= o) sc += u;
    }
    if (t == 63) wtot = sc;          // wave-0 inclusive total
  }
  __syncthreads();
  if (t < 128) {
    int ex = bpad[b] + ((t >= 64) ? wtot : 0) + sc - pv;   // padded start
    lcur[t] = ex;
    if (t < nn) {
      rowp[nb0 + t] = ex;
      dis[nb0 + t] = rsqrtf((float)(v + 1));
      for (int p = ex + v; p < ex + pv; ++p) col[p] = (unsigned short)N;
    }
  }
  __syncthreads();
  const int s0 = off2[b * NB_SPLIT];
  const int s1 = (b + 1 < nbucket) ? off2[(b + 1) * NB_SPLIT] : E;
  for (int i = s0 + t; i < s1; i += 256) {
    unsigned p = (unsigned)tmp[i];
    int j = (int)((p >> 16) & ((1u << BUCKET_SHIFT) - 1));
    int pos = atomicAdd(&lcur[j], 1);
    col[pos] = (unsigned short)(p & 0xffffu);
  }
}

// Zero row N of both blocked activation buffers (gather target for pads).
// Runs AFTER k_csrB (tmp aliases bufB; slice 0's row N overlaps it).
__global__ void k_zfill(float* __restrict__ bufA, float* __restrict__ bufB,
                        int N, int slStride) {
  const int t = threadIdx.x;           // 256 = 2 bufs x 8 slices x 16 floats
  const int bi = t >> 7, si = (t >> 4) & 7, ci = t & 15;
  float* bp = bi ? bufB : bufA;
  bp[(size_t)si * slStride + (size_t)N * 16 + ci] = 0.f;
}

// 3-dim aggregation (pads guarded by s < n).
// PRESCALE=1: out3[i] = dis[i] * (sum_e in3[s]*dis[s] + in3[i]*dis[i])
// PRESCALE=0: out3[i] = bias + dis[i] * (sum_e in3[s] + in3[i])   (in3 pre-scaled)
template <int PRESCALE>
__global__ void k_agg3(const float* __restrict__ in3, float* __restrict__ out3,
                       const int* __restrict__ rowp,
                       const unsigned short* __restrict__ col,
                       const float* __restrict__ dis, const float* __restrict__ bias,
                       int n) {
  int i = blockIdx.x * blockDim.x + threadIdx.x;
  if (i >= n) return;
  const float di = dis[i];
  float a0, a1, a2;
  if (PRESCALE) {
    a0 = in3[i * 3 + 0] * di; a1 = in3[i * 3 + 1] * di; a2 = in3[i * 3 + 2] * di;
  } else {
    a0 = in3[i * 3 + 0]; a1 = in3[i * 3 + 1]; a2 = in3[i * 3 + 2];
  }
  const int e0 = rowp[i], e1 = rowp[i + 1];
  for (int e = e0; e < e1; ++e) {
    int s = col[e];
    if (s >= n) continue;              // padding entry
    if (PRESCALE) {
      float ds_ = dis[s];
      a0 += in3[s * 3 + 0] * ds_;
      a1 += in3[s * 3 + 1] * ds_;
      a2 += in3[s * 3 + 2] * ds_;
    } else {
      a0 += in3[s * 3 + 0];
      a1 += in3[s * 3 + 1];
      a2 += in3[s * 3 + 2];
    }
  }
  a0 *= di; a1 *= di; a2 *= di;
  if (!PRESCALE && bias) { a0 += bias[0]; a1 += bias[1]; a2 += bias[2]; }
  out3[i * 3 + 0] = a0;
  out3[i * 3 + 1] = a1;
  out3[i * 3 + 2] = a2;
}

// Layer 0 matmul: xs = silu(y3 @ W0 + b0) * dis, output in blocked layout.
__global__ void k_mm0(const float* __restrict__ y3, const float* __restrict__ W0,
                      const float* __restrict__ b0, const float* __restrict__ dis,
                      float* __restrict__ out, int n, int slStride) {
  int gid = blockIdx.x * blockDim.x + threadIdx.x;
  int node = gid >> 5;
  int c = (gid & 31) << 2;
  if (node >= n) return;
  float v0 = y3[node * 3 + 0], v1 = y3[node * 3 + 1], v2 = y3[node * 3 + 2];
  float4 a  = *reinterpret_cast<const float4*>(b0 + c);
  float4 w0 = *reinterpret_cast<const float4*>(W0 + 0 * 128 + c);
  float4 w1 = *reinterpret_cast<const float4*>(W0 + 1 * 128 + c);
  float4 w2 = *reinterpret_cast<const float4*>(W0 + 2 * 128 + c);
  a.x += v0 * w0.x + v1 * w1.x + v2 * w2.x;
  a.y += v0 * w0.y + v1 * w1.y + v2 * w2.y;
  a.z += v0 * w0.z + v1 * w1.z + v2 * w2.z;
  a.w += v0 * w0.w + v1 * w1.w + v2 * w2.w;
  const float d = dis[node];
  a.x = silu_f(a.x) * d; a.y = silu_f(a.y) * d;
  a.z = silu_f(a.z) * d; a.w = silu_f(a.w) * d;
  *reinterpret_cast<float4*>(out + (size_t)(c >> 4) * slStride +
                             (size_t)node * 16 + (c & 15)) = a;
}

// 128-dim aggregation, column-sliced + XCD-pinned (blockIdx&7 -> slice -> XCD).
// 8 nodes/wave: lane = nsub(3b)|ch(1b)|c4(2b). Channels take contiguous
// 4-aligned halves of the padded edge region; each iteration: ONE ushort4
// index load + 4 independent gathers (pads gather the hot zero row N).
__global__ __launch_bounds__(256) void k_agg_slice(
    const float* __restrict__ xs, float* __restrict__ y,
    const int* __restrict__ rowp, const unsigned short* __restrict__ col,
    const float* __restrict__ dis, int n, int slStride) {
  const int s = blockIdx.x & 7;
  const int nb = blockIdx.x >> 3;          // 32-node group
  const int t = threadIdx.x;
  const int lane = t & 63;
  const int nsub = lane >> 3;              // node within this wave's 8
  const int ch = (lane >> 2) & 1;          // edge channel 0/1
  const int c4 = (lane & 3) << 2;          // float offset within 16-col slice
  const int node = nb * 32 + (t >> 6) * 8 + nsub;
  const bool valid = node < n;
  int e0 = 0, e1 = 0;
  if (valid) { e0 = rowp[node]; e1 = rowp[node + 1]; }   // padded, mult of 4
  const int P = e1 - e0;
  const int h = ((P >> 1) + 3) & ~3;       // ch0: [e0, e0+h), ch1: [e0+h, e1)
  const int eb = e0 + (ch ? h : 0);
  const int ee = ch ? e1 : (e0 + h);
  const float* __restrict__ xb = xs + (size_t)s * slStride + c4;

  float4 a0 = make_float4(0.f, 0.f, 0.f, 0.f);
  float4 a1 = make_float4(0.f, 0.f, 0.f, 0.f);
  float4 a2 = make_float4(0.f, 0.f, 0.f, 0.f);
  float4 a3 = make_float4(0.f, 0.f, 0.f, 0.f);
  for (int e = eb; e < ee; e += 4) {
    ushort4 idx = *reinterpret_cast<const ushort4*>(col + e);   // 8B aligned
    float4 v0 = *reinterpret_cast<const float4*>(xb + (size_t)idx.x * 16);
    float4 v1 = *reinterpret_cast<const float4*>(xb + (size_t)idx.y * 16);
    float4 v2 = *reinterpret_cast<const float4*>(xb + (size_t)idx.z * 16);
    float4 v3 = *reinterpret_cast<const float4*>(xb + (size_t)idx.w * 16);
    a0.x += v0.x; a0.y += v0.y; a0.z += v0.z; a0.w += v0.w;
    a1.x += v1.x; a1.y += v1.y; a1.z += v1.z; a1.w += v1.w;
    a2.x += v2.x; a2.y += v2.y; a2.z += v2.z; a2.w += v2.w;
    a3.x += v3.x; a3.y += v3.y; a3.z += v3.z; a3.w += v3.w;
  }
  a0.x += a1.x + a2.x + a3.x;
  a0.y += a1.y + a2.y + a3.y;
  a0.z += a1.z + a2.z + a3.z;
  a0.w += a1.w + a2.w + a3.w;
  // combine the two channels (lane bit 2)
  a0.x += __shfl_xor(a0.x, 4);
  a0.y += __shfl_xor(a0.y, 4);
  a0.z += __shfl_xor(a0.z, 4);
  a0.w += __shfl_xor(a0.w, 4);
  if (valid && ch == 0) {
    float4 self = *reinterpret_cast<const float4*>(xb + (size_t)node * 16);
    const float d = dis[node];
    float4 r;
    r.x = (a0.x + self.x) * d;
    r.y = (a0.y + self.y) * d;
    r.z = (a0.z + self.z) * d;
    r.w = (a0.w + self.w) * d;
    *reinterpret_cast<float4*>(y + (size_t)s * slStride + (size_t)node * 16 + c4) = r;
  }
}

// Middle matmul: h = silu(x @ W + b) * dis.  W (64 KB) resident in LDS, staged
// once; main loop has NO barriers and unroll 2 (round-4-proven shape).
// 512 threads, 64-row tile, thread = 4r x 4c. x in blocked layout [8][N+1][16].
// PROJ=1: also project h @ W4 (128->3) and store only the 3-dim result.
template <int PROJ>
__global__ __launch_bounds__(512) void k_mm_w(
    const float* __restrict__ x, const float* __restrict__ W,
    const float* __restrict__ bias, const float* __restrict__ dis,
    float* __restrict__ out, const float* __restrict__ W4, int n, int slStride) {
  __shared__ float ws[128][128];
  const int t = threadIdx.x;
  #pragma unroll
  for (int it = 0; it < 8; ++it) {
    int i = t + it * 512;            // float4 index over 128x128
    *reinterpret_cast<float4*>(&ws[i >> 5][(i & 31) << 2]) =
        *reinterpret_cast<const float4*>(W + (size_t)i * 4);
  }
  __syncthreads();

  const int tc = (t & 31) << 2;      // 4 cols
  const int tr = (t >> 5) << 2;      // 4 rows within the 64-row tile
  const int row0 = blockIdx.x * 64;

  int rb[4];
  #pragma unroll
  for (int r = 0; r < 4; ++r) {
    rb[r] = min(row0 + tr + r, n - 1) * 16;   // clamped; results discarded
  }

  float4 acc[4];
  #pragma unroll
  for (int r = 0; r < 4; ++r) acc[r] = make_float4(0.f, 0.f, 0.f, 0.f);

  #pragma unroll 2
  for (int kk = 0; kk < 128; kk += 4) {
    const float* __restrict__ xk = x + (size_t)(kk >> 4) * slStride + (kk & 15);
    float4 w0 = *reinterpret_cast<const float4*>(&ws[kk + 0][tc]);
    float4 w1 = *reinterpret_cast<const float4*>(&ws[kk + 1][tc]);
    float4 w2 = *reinterpret_cast<const float4*>(&ws[kk + 2][tc]);
    float4 w3 = *reinterpret_cast<const float4*>(&ws[kk + 3][tc]);
    #pragma unroll
    for (int r = 0; r < 4; ++r) {
      float4 xr = *reinterpret_cast<const float4*>(xk + rb[r]);
      acc[r].x += xr.x * w0.x + xr.y * w1.x + xr.z * w2.x + xr.w * w3.x;
      acc[r].y += xr.x * w0.y + xr.y * w1.y + xr.z * w2.y + xr.w * w3.y;
      acc[r].z += xr.x * w0.z + xr.y * w1.z + xr.z * w2.z + xr.w * w3.z;
      acc[r].w += xr.x * w0.w + xr.y * w1.w + xr.z * w2.w + xr.w * w3.w;
    }
  }

  float4 bb = *reinterpret_cast<const float4*>(bias + tc);
  if (PROJ) {
    float w4r[4][3];
    #pragma unroll
    for (int c = 0; c < 4; ++c) {
      w4r[c][0] = W4[(tc + c) * 3 + 0];
      w4r[c][1] = W4[(tc + c) * 3 + 1];
      w4r[c][2] = W4[(tc + c) * 3 + 2];
    }
    #pragma unroll
    for (int r = 0; r < 4; ++r) {
      int row = row0 + tr + r;
      float d = (row < n) ? dis[row] : 0.0f;
      float4 a = acc[r];
      a.x = silu_f(a.x + bb.x) * d;
      a.y = silu_f(a.y + bb.y) * d;
      a.z = silu_f(a.z + bb.z) * d;
      a.w = silu_f(a.w + bb.w) * d;
      float p0 = a.x * w4r[0][0] + a.y * w4r[1][0] + a.z * w4r[2][0] + a.w * w4r[3][0];
      float p1 = a.x * w4r[0][1] + a.y * w4r[1][1] + a.z * w4r[2][1] + a.w * w4r[3][1];
      float p2 = a.x * w4r[0][2] + a.y * w4r[1][2] + a.z * w4r[2][2] + a.w * w4r[3][2];
      #pragma unroll
      for (int m = 16; m >= 1; m >>= 1) {
        p0 += __shfl_xor(p0, m);
        p1 += __shfl_xor(p1, m);
        p2 += __shfl_xor(p2, m);
      }
      if ((t & 31) == 0 && row < n) {
        out[row * 3 + 0] = p0;
        out[row * 3 + 1] = p1;
        out[row * 3 + 2] = p2;
      }
    }
  } else {
    #pragma unroll
    for (int r = 0; r < 4; ++r) {
      int row = row0 + tr + r;
      if (row < n) {
        float4 a = acc[r];
        float d = dis[row];
        a.x = silu_f(a.x + bb.x) * d;
        a.y = silu_f(a.y + bb.y) * d;
        a.z = silu_f(a.z + bb.z) * d;
        a.w = silu_f(a.w + bb.w) * d;
        *reinterpret_cast<float4*>(out + (size_t)(tc >> 4) * slStride +
                                   (size_t)row * 16 + (tc & 15)) = a;
      }
    }
  }
}

extern "C" void kernel_launch(void* const* d_in, const int* in_sizes, int n_in,
                              void* d_out, int out_size, void* d_ws, size_t ws_size,
                              hipStream_t stream) {
  const float* pos = (const float*)d_in[0];
  const int* e32 = (const int*)d_in[1];
  const float* W[5] = {(const float*)d_in[2], (const float*)d_in[4], (const float*)d_in[6],
                       (const float*)d_in[8], (const float*)d_in[10]};
  const float* B[5] = {(const float*)d_in[3], (const float*)d_in[5], (const float*)d_in[7],
                       (const float*)d_in[9], (const float*)d_in[11]};
  float* out = (float*)d_out;

  const int N = in_sizes[0] / 3;
  const int E = in_sizes[1] / 2;
  const int NBUCKET = (N + (1 << BUCKET_SHIFT) - 1) >> BUCKET_SHIFT;  // 391
  const int M = NBUCKET * NB_SPLIT;
  const int chunk = (E + NB_SPLIT - 1) / NB_SPLIT;
  const int slStride = (N + 1) * 16;     // floats per slice (incl. zero row N)

  char* base = (char*)d_ws;
  size_t off = 0;
  auto alloc = [&](size_t bytes) -> void* {
    void* p = base + off;
    off += (bytes + 255) & ~(size_t)255;
    return p;
  };
  float* dis   = (float*)alloc((size_t)N * 4);
  int* rowp    = (int*)alloc((size_t)(N + 1) * 4);
  int* bsum2   = (int*)alloc(128 * 4);
  int* cnt_g   = (int*)alloc((size_t)NBUCKET * 128 * 4);
  int* bpad    = (int*)alloc((size_t)(NBUCKET + 1) * 4);
  int* cnt2    = (int*)alloc((size_t)M * 4);
  int* off2    = (int*)alloc((size_t)M * 4);
  unsigned short* col = (unsigned short*)alloc(((size_t)E + 4 * N) * 2);
  float* y3    = (float*)alloc((size_t)N * 3 * 4);
  float* bufA  = (float*)alloc((size_t)(N + 1) * 128 * 4);
  float* bufB  = (float*)alloc((size_t)(N + 1) * 128 * 4);
  // epack/tmp only live during CSR build; alias the big activation buffers.
  int* epack = (int*)bufA;
  int* tmp   = (int*)bufB;

  const int nblk2 = (M + 1023) / 1024;   // 98

  // --- CSR build (padded) ---
  k_prep<<<NB_SPLIT, 256, 0, stream>>>(e32, epack, cnt2, E, NBUCKET, chunk);
  k_scan1<<<nblk2, 256, 0, stream>>>(cnt2, off2, bsum2, M);
  k_scan2<<<1, 64, 0, stream>>>(bsum2, nblk2);
  k_scanadd<<<(M + 255) / 256, 256, 0, stream>>>(off2, bsum2, M);
  k_split<<<NB_SPLIT, 256, 0, stream>>>(epack, off2, tmp, E, NBUCKET, chunk);
  k_csrA<<<NBUCKET, 256, 0, stream>>>(tmp, off2, cnt_g, bpad, E, NBUCKET);
  k_bscan<<<1, 64, 0, stream>>>(bpad, NBUCKET, rowp, N);
  k_csrB<<<NBUCKET, 256, 0, stream>>>(tmp, off2, cnt_g, bpad, rowp, dis, col, E, NBUCKET, N);
  k_zfill<<<1, 256, 0, stream>>>(bufA, bufB, N, slStride);

  // --- layer 0: 3-dim aggregate (prescale fused) then 3->128 matmul ---
  k_agg3<1><<<(N + 255) / 256, 256, 0, stream>>>(pos, y3, rowp, col, dis, nullptr, N);
  k_mm0<<<(N * 32 + 255) / 256, 256, 0, stream>>>(y3, W[0], B[0], dis, bufA, N, slStride);

  // --- layers 1..2: sliced aggregate (128) then 128x128 matmul + SiLU + dis ---
  const int agg_grid = ((N + 31) / 32) * 8;
  const int mm_grid = (N + 63) / 64;
  for (int l = 1; l <= 2; ++l) {
    k_agg_slice<<<agg_grid, 256, 0, stream>>>(bufA, bufB, rowp, col, dis, N, slStride);
    k_mm_w<0><<<mm_grid, 512, 0, stream>>>(bufB, W[l], B[l], dis, bufA, nullptr, N, slStride);
  }

  // --- layer 3: aggregate, matmul fused with layer-4's 128->3 projection ---
  k_agg_slice<<<agg_grid, 256, 0, stream>>>(bufA, bufB, rowp, col, dis, N, slStride);
  k_mm_w<1><<<mm_grid, 512, 0, stream>>>(bufB, W[3], B[3], dis, y3, W[4], N, slStride);

  // --- layer 4: 3-dim aggregate + bias ---
  k_agg3<0><<<(N + 255) / 256, 256, 0, stream>>>(y3, out, rowp, col, dis, B[4], N);

  (void)n_in; (void)out_size; (void)ws_size;
}

// Round 10
// 320.511 us; speedup vs baseline: 1.2207x; 1.2207x over previous
//
#include <hip/hip_runtime.h>
#include <cstdint>
#include <cstddef>

// ---------------------------------------------------------------------------
// GCN: 5 layers, out = Â (x W) + b per layer, SiLU on layers 0-3.
// Â = D^-1/2 (A + I) D^-1/2 built from edge_index with self-loops.
//  - aggregate in the LOWEST-dim space (linearity): layer 0 aggregates the
//    3-dim input; layer 4's 128->3 matmul is fused into layer 3's GEMM
//    epilogue (PROJ) so layer 4 aggregates 3-dim.
//  - CSR build via LDS-binned multisplit; col as ushort, padded to 4-edge
//    alignment (pads -> zero row N) -> pure ushort4 index loads in agg.
//    Small scans PARALLELIZED (round-9 lesson: 391 serial dependent global
//    iterations in one thread = 40us).
//  - 128-dim aggregation: column-blocked layout [8][N+1][16] + XCD-pinned
//    slices; at its structural wall (~49us = 8M compulsory 64B line fills,
//    round-9 discrimination: miss-slot-rate-bound, not VMEM-issue-bound).
//  - GEMM: W (64 KB) in LDS staged PERMUTED (2-way-free bank access for
//    8-col threads), 4 rows x 8 cols per thread, #pragma unroll 1 +
//    launch_bounds(512,4) to cap VGPR (round-5 lesson: spill = 20x).
// ---------------------------------------------------------------------------

#define NB_SPLIT 256          // workgroups in prep/split passes
#define BUCKET_SHIFT 7        // 128 nodes per bucket

static __device__ __forceinline__ float silu_f(float x) {
  return x / (1.0f + __expf(-x));
}

// Pass A: pack edges to 4B records + per-(bucket, wg) histogram.
// Layout detection (int64 vs int32) folded in.
__global__ __launch_bounds__(256) void k_prep(
    const int* __restrict__ e32, int* __restrict__ epack, int* __restrict__ cnt2,
    int E, int nbucket, int chunk) {
  __shared__ int hist[512];
  __shared__ int nz;
  const int w = blockIdx.x, t = threadIdx.x;
  for (int b = t; b < nbucket; b += 256) hist[b] = 0;
  if (t == 0) nz = 0;
  __syncthreads();
  if (e32[t * 2 + 1] != 0) nz = 1;
  __syncthreads();
  const int f = nz ? 0 : 1;            // 1 -> int64 layout
  const int i0 = w * chunk;
  const int i1 = min(E, i0 + chunk);
  for (int i = i0 + t; i < i1; i += 256) {
    int s, d;
    if (f) { s = e32[2 * i]; d = e32[2 * E + 2 * i]; }
    else   { s = e32[i];     d = e32[E + i]; }
    epack[i] = s | (d << 16);            // requires N <= 65536 (N = 50000)
    atomicAdd(&hist[d >> BUCKET_SHIFT], 1);
  }
  __syncthreads();
  for (int b = t; b < nbucket; b += 256) cnt2[b * NB_SPLIT + w] = hist[b];
}

// Hierarchical exclusive scan, stage 1: 1024 elems/block (4/thread).
__global__ void k_scan1(const int* __restrict__ cnt, int* __restrict__ outp,
                        int* __restrict__ bsum, int n) {
  __shared__ int wsum[4];
  const int t = threadIdx.x;
  const int base = blockIdx.x * 1024 + t * 4;
  int v0 = 0, v1 = 0, v2 = 0, v3 = 0;
  if (base + 0 < n) v0 = cnt[base + 0];
  if (base + 1 < n) v1 = cnt[base + 1];
  if (base + 2 < n) v2 = cnt[base + 2];
  if (base + 3 < n) v3 = cnt[base + 3];
  const int s = v0 + v1 + v2 + v3;
  int sc = s;
  const int lane = t & 63;
  #pragma unroll
  for (int o = 1; o < 64; o <<= 1) {
    int u = __shfl_up(sc, o);
    if (lane >= o) sc += u;
  }
  const int wid = t >> 6;
  if (lane == 63) wsum[wid] = sc;
  __syncthreads();
  int wbase = 0;
  for (int w = 0; w < wid; ++w) wbase += wsum[w];
  const int ex = wbase + sc - s;
  if (base + 0 < n) outp[base + 0] = ex;
  if (base + 1 < n) outp[base + 1] = ex + v0;
  if (base + 2 < n) outp[base + 2] = ex + v0 + v1;
  if (base + 3 < n) outp[base + 3] = ex + v0 + v1 + v2;
  if (t == 0) bsum[blockIdx.x] = wsum[0] + wsum[1] + wsum[2] + wsum[3];
}

// Parallel small exclusive scan, in place, n <= 512 (1 block x 512 threads).
// Optionally writes the grand total to tot0 / tot1.
__global__ __launch_bounds__(512) void k_sscan(
    int* __restrict__ arr, int n, int* __restrict__ tot0, int* __restrict__ tot1) {
  __shared__ int wsum[8];
  const int t = threadIdx.x;
  int v = (t < n) ? arr[t] : 0;
  int sc = v;
  const int lane = t & 63;
  #pragma unroll
  for (int o = 1; o < 64; o <<= 1) {
    int u = __shfl_up(sc, o);
    if (lane >= o) sc += u;
  }
  if (lane == 63) wsum[t >> 6] = sc;
  __syncthreads();
  int wb = 0;
  const int wid = t >> 6;
  for (int w = 0; w < wid; ++w) wb += wsum[w];
  const int ex = wb + sc - v;
  if (t < n) arr[t] = ex;
  if (t == n - 1) {
    int total = ex + v;
    if (tot0) *tot0 = total;
    if (tot1) *tot1 = total;
  }
}

// Stage 3: add block offsets.
__global__ void k_scanadd(int* __restrict__ arr, const int* __restrict__ bsum, int n) {
  int i = blockIdx.x * blockDim.x + threadIdx.x;
  if (i < n) arr[i] += bsum[i >> 10];
}

// Pass B: scatter packed edges into bucket-grouped tmp; each (wg,bucket) owns
// a private contiguous sub-region -> L2 merges the 4B writes into full lines.
__global__ __launch_bounds__(256) void k_split(
    const int* __restrict__ epack, const int* __restrict__ off2,
    int* __restrict__ tmp, int E, int nbucket, int chunk) {
  __shared__ int cur[512];
  const int w = blockIdx.x, t = threadIdx.x;
  for (int b = t; b < nbucket; b += 256) cur[b] = off2[b * NB_SPLIT + w];
  __syncthreads();
  const int i0 = w * chunk;
  const int i1 = min(E, i0 + chunk);
  for (int i = i0 + t; i < i1; i += 256) {
    int p = epack[i];
    int b = (int)(((unsigned)p) >> (16 + BUCKET_SHIFT));
    int pos = atomicAdd(&cur[b], 1);
    tmp[pos] = p;
  }
}

// Pass C1: per bucket, per-node degree histogram + padded bucket total.
__global__ __launch_bounds__(256) void k_csrA(
    const int* __restrict__ tmp, const int* __restrict__ off2,
    int* __restrict__ cnt_g, int* __restrict__ bpad, int E, int nbucket) {
  __shared__ int lcnt[128];
  __shared__ int tot;
  const int b = blockIdx.x, t = threadIdx.x;
  if (t < 128) lcnt[t] = 0;
  if (t == 0) tot = 0;
  __syncthreads();
  const int s0 = off2[b * NB_SPLIT];
  const int s1 = (b + 1 < nbucket) ? off2[(b + 1) * NB_SPLIT] : E;
  for (int i = s0 + t; i < s1; i += 256) {
    atomicAdd(&lcnt[((unsigned)tmp[i] >> 16) & 127u], 1);
  }
  __syncthreads();
  if (t < 128) {
    int v = lcnt[t];
    cnt_g[b * 128 + t] = v;
    atomicAdd(&tot, (v + 3) & ~3);
  }
  __syncthreads();
  if (t == 0) bpad[b] = tot;
}

// Pass C3: per bucket, padded local scan -> rowp/dis/pad-fill, then place
// edges into the padded col array (pads point at zero row N).
__global__ __launch_bounds__(256) void k_csrB(
    const int* __restrict__ tmp, const int* __restrict__ off2,
    const int* __restrict__ cnt_g, const int* __restrict__ bpad,
    int* __restrict__ rowp, float* __restrict__ dis,
    unsigned short* __restrict__ col, int E, int nbucket, int N) {
  __shared__ int lcur[128];
  __shared__ int wtot;
  const int b = blockIdx.x, t = threadIdx.x;
  const int nb0 = b << BUCKET_SHIFT;
  const int nn = min(1 << BUCKET_SHIFT, N - nb0);
  int v = 0, pv = 0, sc = 0;
  if (t < 128) {
    v = cnt_g[b * 128 + t];
    pv = (v + 3) & ~3;
    sc = pv;
    #pragma unroll
    for (int o = 1; o < 64; o <<= 1) {
      int u = __shfl_up(sc, o);
      if ((t & 63) >= o) sc += u;
    }
    if (t == 63) wtot = sc;          // wave-0 inclusive total
  }
  __syncthreads();
  if (t < 128) {
    int ex = bpad[b] + ((t >= 64) ? wtot : 0) + sc - pv;   // padded start
    lcur[t] = ex;
    if (t < nn) {
      rowp[nb0 + t] = ex;
      dis[nb0 + t] = rsqrtf((float)(v + 1));
      for (int p = ex + v; p < ex + pv; ++p) col[p] = (unsigned short)N;
    }
  }
  __syncthreads();
  const int s0 = off2[b * NB_SPLIT];
  const int s1 = (b + 1 < nbucket) ? off2[(b + 1) * NB_SPLIT] : E;
  for (int i = s0 + t; i < s1; i += 256) {
    unsigned p = (unsigned)tmp[i];
    int j = (int)((p >> 16) & ((1u << BUCKET_SHIFT) - 1));
    int pos = atomicAdd(&lcur[j], 1);
    col[pos] = (unsigned short)(p & 0xffffu);
  }
}

// Zero row N of both blocked activation buffers (gather target for pads).
__global__ void k_zfill(float* __restrict__ bufA, float* __restrict__ bufB,
                        int N, int slStride) {
  const int t = threadIdx.x;           // 256 = 2 bufs x 8 slices x 16 floats
  const int bi = t >> 7, si = (t >> 4) & 7, ci = t & 15;
  float* bp = bi ? bufB : bufA;
  bp[(size_t)si * slStride + (size_t)N * 16 + ci] = 0.f;
}

// 3-dim aggregation (pads guarded by s < n).
template <int PRESCALE>
__global__ void k_agg3(const float* __restrict__ in3, float* __restrict__ out3,
                       const int* __restrict__ rowp,
                       const unsigned short* __restrict__ col,
                       const float* __restrict__ dis, const float* __restrict__ bias,
                       int n) {
  int i = blockIdx.x * blockDim.x + threadIdx.x;
  if (i >= n) return;
  const float di = dis[i];
  float a0, a1, a2;
  if (PRESCALE) {
    a0 = in3[i * 3 + 0] * di; a1 = in3[i * 3 + 1] * di; a2 = in3[i * 3 + 2] * di;
  } else {
    a0 = in3[i * 3 + 0]; a1 = in3[i * 3 + 1]; a2 = in3[i * 3 + 2];
  }
  const int e0 = rowp[i], e1 = rowp[i + 1];
  for (int e = e0; e < e1; ++e) {
    int s = col[e];
    if (s >= n) continue;              // padding entry
    if (PRESCALE) {
      float ds_ = dis[s];
      a0 += in3[s * 3 + 0] * ds_;
      a1 += in3[s * 3 + 1] * ds_;
      a2 += in3[s * 3 + 2] * ds_;
    } else {
      a0 += in3[s * 3 + 0];
      a1 += in3[s * 3 + 1];
      a2 += in3[s * 3 + 2];
    }
  }
  a0 *= di; a1 *= di; a2 *= di;
  if (!PRESCALE && bias) { a0 += bias[0]; a1 += bias[1]; a2 += bias[2]; }
  out3[i * 3 + 0] = a0;
  out3[i * 3 + 1] = a1;
  out3[i * 3 + 2] = a2;
}

// Layer 0 matmul: xs = silu(y3 @ W0 + b0) * dis, output in blocked layout.
__global__ void k_mm0(const float* __restrict__ y3, const float* __restrict__ W0,
                      const float* __restrict__ b0, const float* __restrict__ dis,
                      float* __restrict__ out, int n, int slStride) {
  int gid = blockIdx.x * blockDim.x + threadIdx.x;
  int node = gid >> 5;
  int c = (gid & 31) << 2;
  if (node >= n) return;
  float v0 = y3[node * 3 + 0], v1 = y3[node * 3 + 1], v2 = y3[node * 3 + 2];
  float4 a  = *reinterpret_cast<const float4*>(b0 + c);
  float4 w0 = *reinterpret_cast<const float4*>(W0 + 0 * 128 + c);
  float4 w1 = *reinterpret_cast<const float4*>(W0 + 1 * 128 + c);
  float4 w2 = *reinterpret_cast<const float4*>(W0 + 2 * 128 + c);
  a.x += v0 * w0.x + v1 * w1.x + v2 * w2.x;
  a.y += v0 * w0.y + v1 * w1.y + v2 * w2.y;
  a.z += v0 * w0.z + v1 * w1.z + v2 * w2.z;
  a.w += v0 * w0.w + v1 * w1.w + v2 * w2.w;
  const float d = dis[node];
  a.x = silu_f(a.x) * d; a.y = silu_f(a.y) * d;
  a.z = silu_f(a.z) * d; a.w = silu_f(a.w) * d;
  *reinterpret_cast<float4*>(out + (size_t)(c >> 4) * slStride +
                             (size_t)node * 16 + (c & 15)) = a;
}

// 128-dim aggregation, column-sliced + XCD-pinned (blockIdx&7 -> slice -> XCD).
// 8 nodes/wave; channels take 4-aligned halves; ONE ushort4 index load +
// 4 independent gathers per iteration.
__global__ __launch_bounds__(256) void k_agg_slice(
    const float* __restrict__ xs, float* __restrict__ y,
    const int* __restrict__ rowp, const unsigned short* __restrict__ col,
    const float* __restrict__ dis, int n, int slStride) {
  const int s = blockIdx.x & 7;
  const int nb = blockIdx.x >> 3;          // 32-node group
  const int t = threadIdx.x;
  const int lane = t & 63;
  const int nsub = lane >> 3;              // node within this wave's 8
  const int ch = (lane >> 2) & 1;          // edge channel 0/1
  const int c4 = (lane & 3) << 2;          // float offset within 16-col slice
  const int node = nb * 32 + (t >> 6) * 8 + nsub;
  const bool valid = node < n;
  int e0 = 0, e1 = 0;
  if (valid) { e0 = rowp[node]; e1 = rowp[node + 1]; }   // padded, mult of 4
  const int P = e1 - e0;
  const int h = ((P >> 1) + 3) & ~3;       // ch0: [e0, e0+h), ch1: [e0+h, e1)
  const int eb = e0 + (ch ? h : 0);
  const int ee = ch ? e1 : (e0 + h);
  const float* __restrict__ xb = xs + (size_t)s * slStride + c4;

  float4 a0 = make_float4(0.f, 0.f, 0.f, 0.f);
  float4 a1 = make_float4(0.f, 0.f, 0.f, 0.f);
  float4 a2 = make_float4(0.f, 0.f, 0.f, 0.f);
  float4 a3 = make_float4(0.f, 0.f, 0.f, 0.f);
  for (int e = eb; e < ee; e += 4) {
    ushort4 idx = *reinterpret_cast<const ushort4*>(col + e);   // 8B aligned
    float4 v0 = *reinterpret_cast<const float4*>(xb + (size_t)idx.x * 16);
    float4 v1 = *reinterpret_cast<const float4*>(xb + (size_t)idx.y * 16);
    float4 v2 = *reinterpret_cast<const float4*>(xb + (size_t)idx.z * 16);
    float4 v3 = *reinterpret_cast<const float4*>(xb + (size_t)idx.w * 16);
    a0.x += v0.x; a0.y += v0.y; a0.z += v0.z; a0.w += v0.w;
    a1.x += v1.x; a1.y += v1.y; a1.z += v1.z; a1.w += v1.w;
    a2.x += v2.x; a2.y += v2.y; a2.z += v2.z; a2.w += v2.w;
    a3.x += v3.x; a3.y += v3.y; a3.z += v3.z; a3.w += v3.w;
  }
  a0.x += a1.x + a2.x + a3.x;
  a0.y += a1.y + a2.y + a3.y;
  a0.z += a1.z + a2.z + a3.z;
  a0.w += a1.w + a2.w + a3.w;
  a0.x += __shfl_xor(a0.x, 4);
  a0.y += __shfl_xor(a0.y, 4);
  a0.z += __shfl_xor(a0.z, 4);
  a0.w += __shfl_xor(a0.w, 4);
  if (valid && ch == 0) {
    float4 self = *reinterpret_cast<const float4*>(xb + (size_t)node * 16);
    const float d = dis[node];
    float4 r;
    r.x = (a0.x + self.x) * d;
    r.y = (a0.y + self.y) * d;
    r.z = (a0.z + self.z) * d;
    r.w = (a0.w + self.w) * d;
    *reinterpret_cast<float4*>(y + (size_t)s * slStride + (size_t)node * 16 + c4) = r;
  }
}

// Middle matmul: h = silu(x @ W + b) * dis.  W staged once into LDS in a
// PERMUTED block layout: 4-float col-block b of row k -> slot (b>>1)|((b&1)<<4)
// so the 16 col-threads' two b128 reads are 2-way (free) instead of 4-way.
// 512 threads, 128-row tile, thread = 4 rows x 8 cols (acc 32 VGPR).
// #pragma unroll 1 + launch_bounds(512,4): cap VGPR <= 128 -> 2 blocks/CU.
// PROJ=1: also project h @ W4 (128->3) and store only the 3-dim result.
template <int PROJ>
__global__ __launch_bounds__(512, 4) void k_mm_w(
    const float* __restrict__ x, const float* __restrict__ W,
    const float* __restrict__ bias, const float* __restrict__ dis,
    float* __restrict__ out, const float* __restrict__ W4, int n, int slStride) {
  __shared__ float ws[128][128];
  const int t = threadIdx.x;
  #pragma unroll
  for (int it = 0; it < 8; ++it) {
    int i = t + it * 512;            // float4 index over 128x128
    int k = i >> 5, b = i & 31;
    int slot = (b >> 1) | ((b & 1) << 4);
    *reinterpret_cast<float4*>(&ws[k][slot << 2]) =
        *reinterpret_cast<const float4*>(W + (size_t)i * 4);
  }
  __syncthreads();

  const int tc = t & 15;             // cols 8*tc .. 8*tc+7
  const int tr = (t >> 4) << 2;      // 4 rows within the 128-row tile
  const int row0 = blockIdx.x * 128;

  int rb[4];
  #pragma unroll
  for (int r = 0; r < 4; ++r) {
    rb[r] = min(row0 + tr + r, n - 1) * 16;   // clamped; results discarded
  }

  float4 accA[4], accB[4];
  #pragma unroll
  for (int r = 0; r < 4; ++r) {
    accA[r] = make_float4(0.f, 0.f, 0.f, 0.f);
    accB[r] = make_float4(0.f, 0.f, 0.f, 0.f);
  }

  #pragma unroll 1
  for (int kk = 0; kk < 128; kk += 4) {
    const float* __restrict__ xk = x + (size_t)(kk >> 4) * slStride + (kk & 15);
    float4 xr[4];
    #pragma unroll
    for (int r = 0; r < 4; ++r) {
      xr[r] = *reinterpret_cast<const float4*>(xk + rb[r]);
    }
    #pragma unroll
    for (int j = 0; j < 4; ++j) {
      float4 wA = *reinterpret_cast<const float4*>(&ws[kk + j][tc << 2]);       // slot tc
      float4 wB = *reinterpret_cast<const float4*>(&ws[kk + j][64 + (tc << 2)]); // slot 16+tc
      #pragma unroll
      for (int r = 0; r < 4; ++r) {
        float xv = (j == 0) ? xr[r].x : (j == 1) ? xr[r].y : (j == 2) ? xr[r].z : xr[r].w;
        accA[r].x += xv * wA.x; accA[r].y += xv * wA.y;
        accA[r].z += xv * wA.z; accA[r].w += xv * wA.w;
        accB[r].x += xv * wB.x; accB[r].y += xv * wB.y;
        accB[r].z += xv * wB.z; accB[r].w += xv * wB.w;
      }
    }
  }

  float4 bbA = *reinterpret_cast<const float4*>(bias + tc * 8);
  float4 bbB = *reinterpret_cast<const float4*>(bias + tc * 8 + 4);
  if (PROJ) {
    float w4r[8][3];
    #pragma unroll
    for (int c = 0; c < 8; ++c) {
      w4r[c][0] = W4[(tc * 8 + c) * 3 + 0];
      w4r[c][1] = W4[(tc * 8 + c) * 3 + 1];
      w4r[c][2] = W4[(tc * 8 + c) * 3 + 2];
    }
    #pragma unroll
    for (int r = 0; r < 4; ++r) {
      int row = row0 + tr + r;
      float d = (row < n) ? dis[row] : 0.0f;
      float4 a = accA[r], b4 = accB[r];
      a.x = silu_f(a.x + bbA.x) * d;  a.y = silu_f(a.y + bbA.y) * d;
      a.z = silu_f(a.z + bbA.z) * d;  a.w = silu_f(a.w + bbA.w) * d;
      b4.x = silu_f(b4.x + bbB.x) * d; b4.y = silu_f(b4.y + bbB.y) * d;
      b4.z = silu_f(b4.z + bbB.z) * d; b4.w = silu_f(b4.w + bbB.w) * d;
      float p0 = a.x * w4r[0][0] + a.y * w4r[1][0] + a.z * w4r[2][0] + a.w * w4r[3][0]
               + b4.x * w4r[4][0] + b4.y * w4r[5][0] + b4.z * w4r[6][0] + b4.w * w4r[7][0];
      float p1 = a.x * w4r[0][1] + a.y * w4r[1][1] + a.z * w4r[2][1] + a.w * w4r[3][1]
               + b4.x * w4r[4][1] + b4.y * w4r[5][1] + b4.z * w4r[6][1] + b4.w * w4r[7][1];
      float p2 = a.x * w4r[0][2] + a.y * w4r[1][2] + a.z * w4r[2][2] + a.w * w4r[3][2]
               + b4.x * w4r[4][2] + b4.y * w4r[5][2] + b4.z * w4r[6][2] + b4.w * w4r[7][2];
      #pragma unroll
      for (int m = 8; m >= 1; m >>= 1) {   // reduce across the 16 col-threads
        p0 += __shfl_xor(p0, m);
        p1 += __shfl_xor(p1, m);
        p2 += __shfl_xor(p2, m);
      }
      if ((t & 15) == 0 && row < n) {
        out[row * 3 + 0] = p0;
        out[row * 3 + 1] = p1;
        out[row * 3 + 2] = p2;
      }
    }
  } else {
    #pragma unroll
    for (int r = 0; r < 4; ++r) {
      int row = row0 + tr + r;
      if (row < n) {
        float d = dis[row];
        float4 a = accA[r], b4 = accB[r];
        a.x = silu_f(a.x + bbA.x) * d;  a.y = silu_f(a.y + bbA.y) * d;
        a.z = silu_f(a.z + bbA.z) * d;  a.w = silu_f(a.w + bbA.w) * d;
        b4.x = silu_f(b4.x + bbB.x) * d; b4.y = silu_f(b4.y + bbB.y) * d;
        b4.z = silu_f(b4.z + bbB.z) * d; b4.w = silu_f(b4.w + bbB.w) * d;
        // cols 8tc..8tc+7: slice = tc>>1, in-slice offset = (tc&1)*8
        float* dst = out + (size_t)(tc >> 1) * slStride +
                     (size_t)row * 16 + ((tc & 1) << 3);
        *reinterpret_cast<float4*>(dst) = a;
        *reinterpret_cast<float4*>(dst + 4) = b4;
      }
    }
  }
}

extern "C" void kernel_launch(void* const* d_in, const int* in_sizes, int n_in,
                              void* d_out, int out_size, void* d_ws, size_t ws_size,
                              hipStream_t stream) {
  const float* pos = (const float*)d_in[0];
  const int* e32 = (const int*)d_in[1];
  const float* W[5] = {(const float*)d_in[2], (const float*)d_in[4], (const float*)d_in[6],
                       (const float*)d_in[8], (const float*)d_in[10]};
  const float* B[5] = {(const float*)d_in[3], (const float*)d_in[5], (const float*)d_in[7],
                       (const float*)d_in[9], (const float*)d_in[11]};
  float* out = (float*)d_out;

  const int N = in_sizes[0] / 3;
  const int E = in_sizes[1] / 2;
  const int NBUCKET = (N + (1 << BUCKET_SHIFT) - 1) >> BUCKET_SHIFT;  // 391
  const int M = NBUCKET * NB_SPLIT;
  const int chunk = (E + NB_SPLIT - 1) / NB_SPLIT;
  const int slStride = (N + 1) * 16;     // floats per slice (incl. zero row N)

  char* base = (char*)d_ws;
  size_t off = 0;
  auto alloc = [&](size_t bytes) -> void* {
    void* p = base + off;
    off += (bytes + 255) & ~(size_t)255;
    return p;
  };
  float* dis   = (float*)alloc((size_t)N * 4);
  int* rowp    = (int*)alloc((size_t)(N + 1) * 4);
  int* bsum2   = (int*)alloc(128 * 4);
  int* cnt_g   = (int*)alloc((size_t)NBUCKET * 128 * 4);
  int* bpad    = (int*)alloc((size_t)(NBUCKET + 1) * 4);
  int* cnt2    = (int*)alloc((size_t)M * 4);
  int* off2    = (int*)alloc((size_t)M * 4);
  unsigned short* col = (unsigned short*)alloc(((size_t)E + 4 * N) * 2);
  float* y3    = (float*)alloc((size_t)N * 3 * 4);
  float* bufA  = (float*)alloc((size_t)(N + 1) * 128 * 4);
  float* bufB  = (float*)alloc((size_t)(N + 1) * 128 * 4);
  // epack/tmp only live during CSR build; alias the big activation buffers.
  int* epack = (int*)bufA;
  int* tmp   = (int*)bufB;

  const int nblk2 = (M + 1023) / 1024;   // 98

  // --- CSR build (padded; small scans parallelized) ---
  k_prep<<<NB_SPLIT, 256, 0, stream>>>(e32, epack, cnt2, E, NBUCKET, chunk);
  k_scan1<<<nblk2, 256, 0, stream>>>(cnt2, off2, bsum2, M);
  k_sscan<<<1, 512, 0, stream>>>(bsum2, nblk2, nullptr, nullptr);
  k_scanadd<<<(M + 255) / 256, 256, 0, stream>>>(off2, bsum2, M);
  k_split<<<NB_SPLIT, 256, 0, stream>>>(epack, off2, tmp, E, NBUCKET, chunk);
  k_csrA<<<NBUCKET, 256, 0, stream>>>(tmp, off2, cnt_g, bpad, E, NBUCKET);
  k_sscan<<<1, 512, 0, stream>>>(bpad, NBUCKET, bpad + NBUCKET, rowp + N);
  k_csrB<<<NBUCKET, 256, 0, stream>>>(tmp, off2, cnt_g, bpad, rowp, dis, col, E, NBUCKET, N);
  k_zfill<<<1, 256, 0, stream>>>(bufA, bufB, N, slStride);

  // --- layer 0: 3-dim aggregate (prescale fused) then 3->128 matmul ---
  k_agg3<1><<<(N + 255) / 256, 256, 0, stream>>>(pos, y3, rowp, col, dis, nullptr, N);
  k_mm0<<<(N * 32 + 255) / 256, 256, 0, stream>>>(y3, W[0], B[0], dis, bufA, N, slStride);

  // --- layers 1..2: sliced aggregate (128) then 128x128 matmul + SiLU + dis ---
  const int agg_grid = ((N + 31) / 32) * 8;
  const int mm_grid = (N + 127) / 128;
  for (int l = 1; l <= 2; ++l) {
    k_agg_slice<<<agg_grid, 256, 0, stream>>>(bufA, bufB, rowp, col, dis, N, slStride);
    k_mm_w<0><<<mm_grid, 512, 0, stream>>>(bufB, W[l], B[l], dis, bufA, nullptr, N, slStride);
  }

  // --- layer 3: aggregate, matmul fused with layer-4's 128->3 projection ---
  k_agg_slice<<<agg_grid, 256, 0, stream>>>(bufA, bufB, rowp, col, dis, N, slStride);
  k_mm_w<1><<<mm_grid, 512, 0, stream>>>(bufB, W[3], B[3], dis, y3, W[4], N, slStride);

  // --- layer 4: 3-dim aggregate + bias ---
  k_agg3<0><<<(N + 255) / 256, 256, 0, stream>>>(y3, out, rowp, col, dis, B[4], N);

  (void)n_in; (void)out_size; (void)ws_size;
}